// Round 13
// baseline (85.683 us; speedup 1.0000x reference)
//
#include <hip/hip_runtime.h>
#include <math.h>

// 18-qubit statevector, 2 circuits + |<psi2|psi1>|^2, ONE kernel, no grid
// barriers. Qubit q (reference) <-> global index bit (17-q). CZ chain is
// diagonal: per-layer fold = parity(popc(i & (i>>1) & M)) with static masks.
//
// R13: 1024 threads/block (16 waves -> 4 waves/SIMD), 2 amps/thread
// (1 reg bit, 4 wave bits, 6 lane bits). Single-bit reg index -> re-derived
// minimal visit schedules (layer/CZ ordering verified gate-by-gate):
//   Phase 1 (W bits 0..10, lane=w5..10): V(w1)[init,CZ0,L1w1,L1lane] ->
//     V(w2)[L1w2] -> V(w3)[L1w3] -> V(w4)[L1w4,CZ1,L2w4,L2lane] ->
//     V(w2)[L2w2] -> V(w3)[L2w3,CZ2,L3w3,L3lane] ->
//     V(w4)[L3w4,CZ3,L4w4,L4lane,CZ4,(cons)dRa-lane]   (6 rotations)
//   Phase 2 (x bits 0..10, chunk bits 11..17): T6[L0,CZ0,L1x6,L1lane] ->
//     T7[L1x7,CZ1,L2x7,L2lane] -> T8[L2x8] -> T6[L2x6,CZ2,L3x6,L3lane] ->
//     T7[L3x7] -> T8[L3x8] -> T9[L3x9,CZ3,L4x9,L4lane] -> T10[L4x10] ->
//     T8[L4x8] -> T7[L4x7] -> T6[L4x6,CZ4] (producer stores; 10 rotations)
//     consumer: +dR lanes,dRx6 -> T7[dRx7] -> T8[dRx8] -> T9[dRx9] ->
//     T10[dRx10, dot]                                   (14 rotations)
// CZ4 phase-2 fold is a single 0x7FF mask (== R12's 0x71F|0xE0 split).
// rot() has ONE barrier (write->read); the post-read barrier is redundant:
// consecutive rotations write exactly the per-thread slots they just read.
// All dRX (= RX(is*(x1-x2))) except q6 applied to CONSUMER's psi2 (negated
// angle); dRX(q6) (chunk bit 11) folds into the dot:
// conj(a2[i]) * (cf*psi1[i] - i*sf*psi1[i^2048]).
// Producers (c=0) store + release per-chunk flags; consumers (c=1) poll with
// RELAXED agent-scope loads + one acquire fence, then dot.

#define NQ      18
#define NSTATE  (1 << NQ)
#define TPB     1024
#define MAGIC   0x5EED5EEDu

__device__ __forceinline__ int SW(int i) { return i ^ ((i >> 5) & 31); }

__device__ __forceinline__ float2 cmulf(float2 a, float2 b) {
    return make_float2(a.x * b.x - a.y * b.y, a.x * b.y + a.y * b.x);
}

// cross-lane xor: DPP quad_perm for masks 1,2 (VALU pipe); bpermute otherwise
__device__ __forceinline__ float lxor(float x, int j) {
    if (j == 0) {
        int v = __float_as_int(x);
        return __int_as_float(__builtin_amdgcn_update_dpp(v, v, 0xB1, 0xF, 0xF, false));
    }
    if (j == 1) {
        int v = __float_as_int(x);
        return __int_as_float(__builtin_amdgcn_update_dpp(v, v, 0x4E, 0xF, 0xF, false));
    }
    return __shfl_xor(x, 1 << j, 64);
}

__device__ __forceinline__ void cpair(
    float& a0r, float& a0i, float& a1r, float& a1i,
    float u00r, float u00i, float u01r, float u01i,
    float u10r, float u10i, float u11r, float u11i)
{
    float n0r = u00r * a0r - u00i * a0i + u01r * a1r - u01i * a1i;
    float n0i = u00r * a0i + u00i * a0r + u01r * a1i + u01i * a1r;
    float n1r = u10r * a0r - u10i * a0i + u11r * a1r - u11i * a1i;
    float n1i = u10r * a0i + u10i * a0r + u11r * a1i + u11i * a1r;
    a0r = n0r; a0i = n0i; a1r = n1r; a1i = n1i;
}

// gate on the single reg bit (amps 0,1)
__device__ __forceinline__ void reg_gate2(float (&ar)[2], float (&ai)[2],
                                          const float2* up)
{
    cpair(ar[0], ai[0], ar[1], ai[1],
          up[0].x, up[0].y, up[1].x, up[1].y, up[2].x, up[2].y, up[3].x, up[3].y);
}

__device__ __forceinline__ void lane_gate2(float (&ar)[2], float (&ai)[2],
                                           const float2* up, int lane, int j)
{
    float u00r = up[0].x, u00i = up[0].y, u01r = up[1].x, u01i = up[1].y;
    float u10r = up[2].x, u10i = up[2].y, u11r = up[3].x, u11i = up[3].y;
    int side = (lane >> j) & 1;
    float car = side ? u11r : u00r, cai = side ? u11i : u00i;
    float cbr = side ? u10r : u01r, cbi = side ? u10i : u01i;
#pragma unroll
    for (int r = 0; r < 2; ++r) {
        float pr = lxor(ar[r], j);
        float pi = lxor(ai[r], j);
        float mr = ar[r], mi = ai[r];
        ar[r] = car * mr - cai * mi + cbr * pr - cbi * pi;
        ai[r] = car * mi + cai * mr + cbr * pi + cbi * pr;
    }
}

// ---------------- the fused kernel ------------------------------------------
__global__ __launch_bounds__(TPB) void sim_kernel(
    float2* __restrict__ states,
    const float* __restrict__ x1, const float* __restrict__ x2,
    const float* __restrict__ iscale, const float* __restrict__ var,
    double* __restrict__ acc, unsigned* __restrict__ cnt,
    unsigned* __restrict__ flags, float* __restrict__ out)
{
    __shared__ float sre[2048], sim_[2048];
    __shared__ float2 sUa[5 * 11 * 4];   // phase-1 gates: [l][w], q = 10-w
    __shared__ float2 sUb[5 * 11 * 4];   // phase-2 gates: [l][w], q = 17-w
    __shared__ float2 sDa[6 * 4];        // RX(-d), phase-1: j -> q=5-j (consumer)
    __shared__ float2 sDb[11 * 4];       // RX(-d), phase-2: w -> q=17-w (consumer)
    __shared__ double wr[16], wi[16];

    int blk = blockIdx.x, t = threadIdx.x, lane = t & 63, wave = t >> 6;
    int c = blk >> 7, gc = blk & 127;
    int wv0 = wave & 1, wv1 = (wave >> 1) & 1, wv2 = (wave >> 2) & 1,
        wv3 = (wave >> 3) & 1;
    const float* xv = c ? x2 : x1;

    // init (block 0): zero acc/cnt, release init flag (release = writeback).
    if (blk == 0 && t == 0) {
        acc[0] = 0.0; acc[1] = 0.0; *cnt = 0u;
        __hip_atomic_store(&flags[128 * 16], MAGIC, __ATOMIC_RELEASE,
                           __HIP_MEMORY_SCOPE_AGENT);
    }

    // ---- compose gate matrices (fp32 sincosf) ----
    if (t < 110) {
        int which = t >= 55;
        int tt = which ? t - 55 : t;
        int l = tt / 11, w = tt % 11;
        int q = which ? (17 - w) : (10 - w);
        float tx = iscale[l * NQ + q] * xv[q];
        float ty = var[l * 2 * NQ + q];
        float tz = var[l * 2 * NQ + NQ + q];
        float sx, cx, sy, cy, sz, cz;
        sincosf(tx * 0.5f, &sx, &cx);
        sincosf(ty * 0.5f, &sy, &cy);
        sincosf(tz * 0.5f, &sz, &cz);
        float m00r = cy * cx,  m00i =  sy * sx;
        float m01r = -sy * cx, m01i = -cy * sx;
        float m10r = sy * cx,  m10i = -cy * sx;
        float m11r = cy * cx,  m11i = -sy * sx;
        float2* up = which ? &sUb[(l * 11 + w) * 4] : &sUa[(l * 11 + w) * 4];
        up[0] = make_float2(m00r * cz + m00i * sz, m00i * cz - m00r * sz);
        up[1] = make_float2(m01r * cz + m01i * sz, m01i * cz - m01r * sz);
        up[2] = make_float2(m10r * cz - m10i * sz, m10i * cz + m10r * sz);
        up[3] = make_float2(m11r * cz - m11i * sz, m11i * cz + m11r * sz);
    } else if (t < 127) {
        int isb = t >= 116;
        int j = isb ? (t - 116) : (t - 110);
        int q = isb ? (17 - j) : (5 - j);
        float d = iscale[5 * NQ + q] * (x1[q] - x2[q]);
        float sn, cs;
        sincosf(d * 0.5f, &sn, &cs);
        // RX(-d): [cs, +i sn; +i sn, cs] (consumer side)
        float2* up = isb ? &sDb[j * 4] : &sDa[j * 4];
        up[0] = make_float2(cs, 0.f);  up[1] = make_float2(0.f, sn);
        up[2] = make_float2(0.f, sn);  up[3] = make_float2(cs, 0.f);
    }
    __syncthreads();

    float ar[2], ai[2];
    // phase-1 mappings: W bits; reg bit = w_k, others wv0..wv3 ascending
    auto V1 = [&](int r) { return wv0 | (r << 1) | (wv1 << 2) | (wv2 << 3)
                                | (wv3 << 4) | (lane << 5); };
    auto V2 = [&](int r) { return wv0 | (wv1 << 1) | (r << 2) | (wv2 << 3)
                                | (wv3 << 4) | (lane << 5); };
    auto V3 = [&](int r) { return wv0 | (wv1 << 1) | (wv2 << 2) | (r << 3)
                                | (wv3 << 4) | (lane << 5); };
    auto V4 = [&](int r) { return wv0 | (wv1 << 1) | (wv2 << 2) | (wv3 << 3)
                                | (r << 4) | (lane << 5); };
    // phase-2 mappings: x bits; reg bit = x_k, others wv0..wv3 ascending
    auto T6  = [&](int r) { return lane | (r << 6) | (wv0 << 7) | (wv1 << 8)
                                 | (wv2 << 9) | (wv3 << 10); };
    auto T7  = [&](int r) { return lane | (wv0 << 6) | (r << 7) | (wv1 << 8)
                                 | (wv2 << 9) | (wv3 << 10); };
    auto T8  = [&](int r) { return lane | (wv0 << 6) | (wv1 << 7) | (r << 8)
                                 | (wv2 << 9) | (wv3 << 10); };
    auto T9  = [&](int r) { return lane | (wv0 << 6) | (wv1 << 7) | (wv2 << 8)
                                 | (r << 9) | (wv3 << 10); };
    auto T10 = [&](int r) { return lane | (wv0 << 6) | (wv1 << 7) | (wv2 << 8)
                                 | (wv3 << 9) | (r << 10); };
    // single-barrier rotation: consecutive rotations write exactly the
    // per-thread slots they just read -> no post-read barrier needed.
    auto rot = [&](auto from, auto to) {
#pragma unroll
        for (int r = 0; r < 2; ++r) { int s = SW(from(r)); sre[s] = ar[r]; sim_[s] = ai[r]; }
        __syncthreads();
#pragma unroll
        for (int r = 0; r < 2; ++r) { int s = SW(to(r)); ar[r] = sre[s]; ai[r] = sim_[s]; }
    };
    auto Ua = [&](int l, int w) -> const float2* { return &sUa[(l * 11 + w) * 4]; };
    auto Ub = [&](int l, int w) -> const float2* { return &sUb[(l * 11 + w) * 4]; };
    auto czfold = [&](unsigned M, auto gidx) {
#pragma unroll
        for (int r = 0; r < 2; ++r) {
            int i = gidx(r);
            if (__popc(i & (i >> 1) & M) & 1) { ar[r] = -ar[r]; ai[r] = -ai[r]; }
        }
    };
    auto gV1 = [&](int r) { return V1(r) << 7; };
    auto gV2 = [&](int r) { return V2(r) << 7; };
    auto gV3 = [&](int r) { return V3(r) << 7; };
    auto gV4 = [&](int r) { return V4(r) << 7; };
    auto gT6 = [&](int r) { return (gc << 11) | T6(r); };
    auto gT7 = [&](int r) { return (gc << 11) | T7(r); };
    auto gT8 = [&](int r) { return (gc << 11) | T8(r); };
    auto gT9 = [&](int r) { return (gc << 11) | T9(r); };

    // ================= PHASE 1 (every block, own circuit) ==================
    // S1 [V1, reg=w1]: product init (L0 all), CZ0, L1w1, L1 lanes
    {
        float2 com = make_float2(1.f, 0.f);
        const float2* u0 = Ua(0, 0); com = cmulf(com, wv0 ? u0[2] : u0[0]);
        const float2* u2 = Ua(0, 2); com = cmulf(com, wv1 ? u2[2] : u2[0]);
        const float2* u3 = Ua(0, 3); com = cmulf(com, wv2 ? u3[2] : u3[0]);
        const float2* u4 = Ua(0, 4); com = cmulf(com, wv3 ? u4[2] : u4[0]);
#pragma unroll
        for (int j = 0; j < 6; ++j) {
            const float2* u = Ua(0, 5 + j);
            com = cmulf(com, ((lane >> j) & 1) ? u[2] : u[0]);
        }
        const float2* u1 = Ua(0, 1);
#pragma unroll
        for (int r = 0; r < 2; ++r) {
            float2 f = cmulf(com, r ? u1[2] : u1[0]);
            ar[r] = f.x; ai[r] = f.y;
        }
    }
    czfold(0x1FF80u, gV1);                        // CZ0
    reg_gate2(ar, ai, Ua(1, 1));                  // L1 w1
#pragma unroll
    for (int j = 0; j < 6; ++j) lane_gate2(ar, ai, Ua(1, 5 + j), lane, j);
    rot(V1, V2);
    reg_gate2(ar, ai, Ua(1, 2));                  // S2: L1 w2
    rot(V2, V3);
    reg_gate2(ar, ai, Ua(1, 3));                  // S3: L1 w3
    rot(V3, V4);
    // S4 [V4]: L1w4, CZ1, L2w4, L2 lanes
    reg_gate2(ar, ai, Ua(1, 4));
    czfold(0x1FF00u, gV4);                        // CZ1
    reg_gate2(ar, ai, Ua(2, 4));
#pragma unroll
    for (int j = 0; j < 6; ++j) lane_gate2(ar, ai, Ua(2, 5 + j), lane, j);
    rot(V4, V2);
    reg_gate2(ar, ai, Ua(2, 2));                  // S5: L2 w2
    rot(V2, V3);
    // S6 [V3]: L2w3, CZ2, L3w3, L3 lanes
    reg_gate2(ar, ai, Ua(2, 3));
    czfold(0x1FE00u, gV3);                        // CZ2
    reg_gate2(ar, ai, Ua(3, 3));
#pragma unroll
    for (int j = 0; j < 6; ++j) lane_gate2(ar, ai, Ua(3, 5 + j), lane, j);
    rot(V3, V4);
    // S7 [V4]: L3w4, CZ3, L4w4, L4 lanes, CZ4, (consumer) dRa lanes
    reg_gate2(ar, ai, Ua(3, 4));
    czfold(0x1FC00u, gV4);                        // CZ3
    reg_gate2(ar, ai, Ua(4, 4));
#pragma unroll
    for (int j = 0; j < 6; ++j) lane_gate2(ar, ai, Ua(4, 5 + j), lane, j);
    czfold(0x1F800u, gV4);                        // CZ4 phase-1 part
    if (c == 1) {
#pragma unroll
        for (int j = 0; j < 6; ++j) lane_gate2(ar, ai, &sDa[j * 4], lane, j);
    }
    // transition: publish (V4 layout), sparse-gather phase-2 init (T6)
#pragma unroll
    for (int r = 0; r < 2; ++r) { int s = SW(V4(r)); sre[s] = ar[r]; sim_[s] = ai[r]; }
    __syncthreads();
#pragma unroll
    for (int r = 0; r < 2; ++r) {
        int x = T6(r);
        if ((x & 127) == 0) {
            int Wv = (gc << 4) | (x >> 7);
            int s = SW(Wv);
            ar[r] = sre[s]; ai[r] = sim_[s];
        } else { ar[r] = 0.f; ai[r] = 0.f; }
    }
    __syncthreads();   // gather reads arbitrary slots: barrier before next write

    // ================= PHASE 2 (chunk gc, circuit c) =======================
    // v1 [T6]: L0 lanes, L0x6, CZ0, L1 lanes, L1x6
#pragma unroll
    for (int j = 0; j < 6; ++j) lane_gate2(ar, ai, Ub(0, j), lane, j);
    reg_gate2(ar, ai, Ub(0, 6));
    czfold(0x7Fu, gT6);                           // CZ0
#pragma unroll
    for (int j = 0; j < 6; ++j) lane_gate2(ar, ai, Ub(1, j), lane, j);
    reg_gate2(ar, ai, Ub(1, 6));
    rot(T6, T7);
    // v2 [T7]: L1x7, CZ1, L2x7, L2 lanes
    reg_gate2(ar, ai, Ub(1, 7));
    czfold(0xFFu, gT7);                           // CZ1
    reg_gate2(ar, ai, Ub(2, 7));
#pragma unroll
    for (int j = 0; j < 6; ++j) lane_gate2(ar, ai, Ub(2, j), lane, j);
    rot(T7, T8);
    reg_gate2(ar, ai, Ub(2, 8));                  // v3: L2x8
    rot(T8, T6);
    // v4 [T6]: L2x6, CZ2, L3x6, L3 lanes
    reg_gate2(ar, ai, Ub(2, 6));
    czfold(0x1FFu, gT6);                          // CZ2
    reg_gate2(ar, ai, Ub(3, 6));
#pragma unroll
    for (int j = 0; j < 6; ++j) lane_gate2(ar, ai, Ub(3, j), lane, j);
    rot(T6, T7);
    reg_gate2(ar, ai, Ub(3, 7));                  // v5: L3x7
    rot(T7, T8);
    reg_gate2(ar, ai, Ub(3, 8));                  // v6: L3x8
    rot(T8, T9);
    // v7 [T9]: L3x9, CZ3, L4x9, L4 lanes
    reg_gate2(ar, ai, Ub(3, 9));
    czfold(0x3FFu, gT9);                          // CZ3
    reg_gate2(ar, ai, Ub(4, 9));
#pragma unroll
    for (int j = 0; j < 6; ++j) lane_gate2(ar, ai, Ub(4, j), lane, j);
    rot(T9, T10);
    reg_gate2(ar, ai, Ub(4, 10));                 // v8: L4x10
    rot(T10, T8);
    reg_gate2(ar, ai, Ub(4, 8));                  // v9: L4x8
    rot(T8, T7);
    reg_gate2(ar, ai, Ub(4, 7));                  // v10: L4x7
    rot(T7, T6);
    // v11 [T6]: L4x6, CZ4 (full phase-2 mask incl. chunk-bit pair)
    reg_gate2(ar, ai, Ub(4, 6));
    czfold(0x7FFu, gT6);                          // CZ4 phase-2 part

    if (c == 0) {
        // -------- producer: store chunk (T6 layout), release flag --------
#pragma unroll
        for (int r = 0; r < 2; ++r) {
            int i = (gc << 11) | T6(r);
            states[i] = make_float2(ar[r], ai[r]);
        }
        __syncthreads();            // all waves' stores issued
        if (t == 0) {
            __hip_atomic_store(&flags[gc * 16], MAGIC, __ATOMIC_RELEASE,
                               __HIP_MEMORY_SCOPE_AGENT);
        }
    } else {
        // consumer: dR lanes + x6..x10 via tail visits, then poll + dot
#pragma unroll
        for (int j = 0; j < 6; ++j) lane_gate2(ar, ai, &sDb[j * 4], lane, j);
        reg_gate2(ar, ai, &sDb[6 * 4]);           // dR x6
        rot(T6, T7);
        reg_gate2(ar, ai, &sDb[7 * 4]);           // dR x7
        rot(T7, T8);
        reg_gate2(ar, ai, &sDb[8 * 4]);           // dR x8
        rot(T8, T9);
        reg_gate2(ar, ai, &sDb[9 * 4]);           // dR x9
        rot(T9, T10);
        reg_gate2(ar, ai, &sDb[10 * 4]);          // dR x10

        float d6 = iscale[5 * NQ + 6] * (x1[6] - x2[6]);
        float sn6, cs6;
        sincosf(d6 * 0.5f, &sn6, &cs6);
        float cf = cs6, sf = sn6;

        if (t == 0) {
            // RELAXED agent-scope polls read the LLC directly (no per-poll
            // cache invalidate); one acquire fence after all flags confirm.
            while (__hip_atomic_load(&flags[gc * 16], __ATOMIC_RELAXED,
                                     __HIP_MEMORY_SCOPE_AGENT) != MAGIC)
                __builtin_amdgcn_s_sleep(1);
            while (__hip_atomic_load(&flags[(gc ^ 1) * 16], __ATOMIC_RELAXED,
                                     __HIP_MEMORY_SCOPE_AGENT) != MAGIC)
                __builtin_amdgcn_s_sleep(1);
            while (__hip_atomic_load(&flags[128 * 16], __ATOMIC_RELAXED,
                                     __HIP_MEMORY_SCOPE_AGENT) != MAGIC)
                __builtin_amdgcn_s_sleep(1);
            __builtin_amdgcn_fence(__ATOMIC_ACQUIRE, "agent");
        }
        __syncthreads();            // whole block proceeds after the fence

        double accr = 0.0, acci = 0.0;
#pragma unroll
        for (int r = 0; r < 2; ++r) {
            int i = (gc << 11) | T10(r);
            float2 p1 = states[i];
            float2 pp = states[i ^ 2048];
            // (RX6(+d6) psi1)[i] = cf*psi1[i] - i*sf*psi1[i^b11]
            float gr = cf * p1.x + sf * pp.y;
            float gi = cf * p1.y - sf * pp.x;
            // conj(a2) * psi1'
            accr += (double)ar[r] * gr + (double)ai[r] * gi;
            acci += (double)ar[r] * gi - (double)ai[r] * gr;
        }
        for (int o = 32; o > 0; o >>= 1) {
            accr += __shfl_down(accr, o, 64);
            acci += __shfl_down(acci, o, 64);
        }
        if (lane == 0) { wr[wave] = accr; wi[wave] = acci; }
        __syncthreads();
        if (t == 0) {
            double br = 0.0, bi = 0.0;
#pragma unroll
            for (int w = 0; w < 16; ++w) { br += wr[w]; bi += wi[w]; }
            atomicAdd(&acc[0], br);
            atomicAdd(&acc[1], bi);
            __threadfence();
            unsigned old = atomicAdd(cnt, 1u);
            if (old == 127u) {
                double fr = atomicAdd(&acc[0], 0.0);
                double fi = atomicAdd(&acc[1], 0.0);
                out[0] = (float)(fr * fr + fi * fi);
            }
        }
    }
}

// ---------------- launch ----------------------------------------------------
extern "C" void kernel_launch(void* const* d_in, const int* in_sizes, int n_in,
                              void* d_out, int out_size, void* d_ws, size_t ws_size,
                              hipStream_t stream)
{
    const float* x1 = (const float*)d_in[0];
    const float* x2 = (const float*)d_in[1];
    const float* iscale = (const float*)d_in[2];
    const float* var = (const float*)d_in[3];
    float* out = (float*)d_out;

    // ws layout: [8192] acc (2 doubles); [8320] cnt; [16384] flags (129 x 64B
    // slots, ends 24640); [65536, 65536+2MB) psi1 statevector.
    double*   acc    = (double*)((char*)d_ws + 8192);
    unsigned* cnt    = (unsigned*)((char*)d_ws + 8320);
    unsigned* flags  = (unsigned*)((char*)d_ws + 16384);
    float2*   states = (float2*)((char*)d_ws + 65536);

    sim_kernel<<<256, TPB, 0, stream>>>(states, x1, x2, iscale, var,
                                        acc, cnt, flags, out);
}

// Round 14
// 84.418 us; speedup vs baseline: 1.0150x; 1.0150x over previous
//
#include <hip/hip_runtime.h>
#include <math.h>

// 18-qubit statevector, 2 circuits + |<psi2|psi1>|^2, ONE kernel, no grid
// barriers. Qubit q (reference) <-> global index bit (17-q). CZ chain is
// diagonal: per-layer fold = parity(popc(i & (i>>1) & M)) with static masks.
//
// R14 = R12 (the bracketed-optimal operating point: 512 thr/block, 2 waves/
// SIMD, 4 amps/thread) + single-barrier rot() (validated by R13: consecutive
// rotations write exactly the per-thread slots their owner just read -> the
// post-read barrier is redundant; the transition gather keeps both barriers
// since it reads non-owned slots).
//   Phase 1 (window W = bits 7..17): V1{w1,w2} -> V2{w3,w4} -> V3{w2,w3}
//     -> V2{w3,w4} -> V1, 4 rotations.
//   Phase 2 (window x = bits 0..10, chunk bits 11..17): T1{6,7} -> T2{8,9}
//     -> T1 -> T2 -> T1 -> T6{9,10} (+ consumer-only T1 -> T8{8,10}).
// All dRX = RX(is*(x1-x2)) gates except q6 on the CONSUMER's psi2 (negated
// angle); dRX(q6) (bit 11 = chunk bit) folds into the dot:
// conj(a2[i]) * (cf*psi1[i] - i*sf*psi1[i^2048]).
// Producers (c=0, plain circuit) store + release per-chunk flags; consumers
// (c=1) poll with RELAXED agent-scope loads + one acquire fence, then dot.

#define NQ      18
#define NSTATE  (1 << NQ)
#define TPB     512
#define MAGIC   0x5EED5EEDu

__device__ __forceinline__ int SW(int i) { return i ^ ((i >> 5) & 31); }

__device__ __forceinline__ float2 cmulf(float2 a, float2 b) {
    return make_float2(a.x * b.x - a.y * b.y, a.x * b.y + a.y * b.x);
}

// cross-lane xor: DPP quad_perm for masks 1,2 (VALU pipe); bpermute otherwise
__device__ __forceinline__ float lxor(float x, int j) {
    if (j == 0) {
        int v = __float_as_int(x);
        return __int_as_float(__builtin_amdgcn_update_dpp(v, v, 0xB1, 0xF, 0xF, false));
    }
    if (j == 1) {
        int v = __float_as_int(x);
        return __int_as_float(__builtin_amdgcn_update_dpp(v, v, 0x4E, 0xF, 0xF, false));
    }
    return __shfl_xor(x, 1 << j, 64);
}

__device__ __forceinline__ void cpair(
    float& a0r, float& a0i, float& a1r, float& a1i,
    float u00r, float u00i, float u01r, float u01i,
    float u10r, float u10i, float u11r, float u11i)
{
    float n0r = u00r * a0r - u00i * a0i + u01r * a1r - u01i * a1i;
    float n0i = u00r * a0i + u00i * a0r + u01r * a1i + u01i * a1r;
    float n1r = u10r * a0r - u10i * a0i + u11r * a1r - u11i * a1i;
    float n1i = u10r * a0i + u10i * a0r + u11r * a1i + u11i * a1r;
    a0r = n0r; a0i = n0i; a1r = n1r; a1i = n1i;
}

template<int RB>
__device__ __forceinline__ void reg_gate4(float (&ar)[4], float (&ai)[4],
                                          const float2* up)
{
    float u00r = up[0].x, u00i = up[0].y, u01r = up[1].x, u01i = up[1].y;
    float u10r = up[2].x, u10i = up[2].y, u11r = up[3].x, u11i = up[3].y;
#pragma unroll
    for (int r = 0; r < 4; ++r) {
        if (r & RB) continue;
        int r1 = r | RB;
        cpair(ar[r], ai[r], ar[r1], ai[r1],
              u00r, u00i, u01r, u01i, u10r, u10i, u11r, u11i);
    }
}

__device__ __forceinline__ void lane_gate4(float (&ar)[4], float (&ai)[4],
                                           const float2* up, int lane, int j)
{
    float u00r = up[0].x, u00i = up[0].y, u01r = up[1].x, u01i = up[1].y;
    float u10r = up[2].x, u10i = up[2].y, u11r = up[3].x, u11i = up[3].y;
    int side = (lane >> j) & 1;
    float car = side ? u11r : u00r, cai = side ? u11i : u00i;
    float cbr = side ? u10r : u01r, cbi = side ? u10i : u01i;
#pragma unroll
    for (int r = 0; r < 4; ++r) {
        float pr = lxor(ar[r], j);
        float pi = lxor(ai[r], j);
        float mr = ar[r], mi = ai[r];
        ar[r] = car * mr - cai * mi + cbr * pr - cbi * pi;
        ai[r] = car * mi + cai * mr + cbr * pi + cbi * pr;
    }
}

// ---------------- the fused kernel ------------------------------------------
__global__ __launch_bounds__(TPB) void sim_kernel(
    float2* __restrict__ states,
    const float* __restrict__ x1, const float* __restrict__ x2,
    const float* __restrict__ iscale, const float* __restrict__ var,
    double* __restrict__ acc, unsigned* __restrict__ cnt,
    unsigned* __restrict__ flags, float* __restrict__ out)
{
    __shared__ float sre[2048], sim_[2048];
    __shared__ float2 sUa[5 * 11 * 4];   // phase-1 gates: [l][w], q = 10-w
    __shared__ float2 sUb[5 * 11 * 4];   // phase-2 gates: [l][w], q = 17-w
    __shared__ float2 sDa[6 * 4];        // RX(-d), phase-1: j -> q=5-j (consumer)
    __shared__ float2 sDb[11 * 4];       // RX(-d), phase-2: w -> q=17-w (consumer)
    __shared__ double wr[8], wi[8];

    int blk = blockIdx.x, t = threadIdx.x, lane = t & 63, wave = t >> 6;
    int c = blk >> 7, gc = blk & 127;
    int wv0 = wave & 1, wv1 = (wave >> 1) & 1, wv2 = (wave >> 2) & 1;
    const float* xv = c ? x2 : x1;

    // init (block 0): zero acc/cnt, release init flag (release = writeback).
    if (blk == 0 && t == 0) {
        acc[0] = 0.0; acc[1] = 0.0; *cnt = 0u;
        __hip_atomic_store(&flags[128 * 16], MAGIC, __ATOMIC_RELEASE,
                           __HIP_MEMORY_SCOPE_AGENT);
    }

    // ---- compose gate matrices (fp32 sincosf) ----
    if (t < 110) {
        int which = t >= 55;
        int tt = which ? t - 55 : t;
        int l = tt / 11, w = tt % 11;
        int q = which ? (17 - w) : (10 - w);
        float tx = iscale[l * NQ + q] * xv[q];
        float ty = var[l * 2 * NQ + q];
        float tz = var[l * 2 * NQ + NQ + q];
        float sx, cx, sy, cy, sz, cz;
        sincosf(tx * 0.5f, &sx, &cx);
        sincosf(ty * 0.5f, &sy, &cy);
        sincosf(tz * 0.5f, &sz, &cz);
        float m00r = cy * cx,  m00i =  sy * sx;
        float m01r = -sy * cx, m01i = -cy * sx;
        float m10r = sy * cx,  m10i = -cy * sx;
        float m11r = cy * cx,  m11i = -sy * sx;
        float2* up = which ? &sUb[(l * 11 + w) * 4] : &sUa[(l * 11 + w) * 4];
        up[0] = make_float2(m00r * cz + m00i * sz, m00i * cz - m00r * sz);
        up[1] = make_float2(m01r * cz + m01i * sz, m01i * cz - m01r * sz);
        up[2] = make_float2(m10r * cz - m10i * sz, m10i * cz + m10r * sz);
        up[3] = make_float2(m11r * cz - m11i * sz, m11i * cz + m11r * sz);
    } else if (t < 127) {
        int isb = t >= 116;
        int j = isb ? (t - 116) : (t - 110);
        int q = isb ? (17 - j) : (5 - j);
        float d = iscale[5 * NQ + q] * (x1[q] - x2[q]);
        float sn, cs;
        sincosf(d * 0.5f, &sn, &cs);
        // RX(-d): [cs, +i sn; +i sn, cs] (consumer side)
        float2* up = isb ? &sDb[j * 4] : &sDa[j * 4];
        up[0] = make_float2(cs, 0.f);  up[1] = make_float2(0.f, sn);
        up[2] = make_float2(0.f, sn);  up[3] = make_float2(cs, 0.f);
    }
    __syncthreads();

    float ar[4], ai[4];
    // phase-1 mappings (bits of W; global i = W<<7); lane = w5..10 always
    auto V1 = [&](int r) { return wv0 | ((r & 1) << 1) | (((r >> 1) & 1) << 2)
                                | (wv1 << 3) | (wv2 << 4) | (lane << 5); };
    auto V2 = [&](int r) { return wv0 | (wv1 << 1) | (wv2 << 2)
                                | ((r & 1) << 3) | (((r >> 1) & 1) << 4) | (lane << 5); };
    auto V3 = [&](int r) { return wv0 | (wv1 << 1) | ((r & 1) << 2)
                                | (((r >> 1) & 1) << 3) | (wv2 << 4) | (lane << 5); };
    // phase-2 mappings (bits of x; global i = (gc<<11)|x); lane = w0..5
    auto T1 = [&](int r) { return lane | ((r & 1) << 6) | (((r >> 1) & 1) << 7)
                                | (wv0 << 8) | (wv1 << 9) | (wv2 << 10); };
    auto T2 = [&](int r) { return lane | (wv0 << 6) | (wv1 << 7)
                                | ((r & 1) << 8) | (((r >> 1) & 1) << 9) | (wv2 << 10); };
    auto T6 = [&](int r) { return lane | (wv0 << 6) | (wv1 << 7) | (wv2 << 8)
                                | ((r & 1) << 9) | (((r >> 1) & 1) << 10); };
    auto T8 = [&](int r) { return lane | (wv0 << 6) | (wv1 << 7)
                                | ((r & 1) << 8) | (wv2 << 9) | (((r >> 1) & 1) << 10); };
    // single-barrier rotation (R13-validated): consecutive rotations write
    // exactly the per-thread slots they just read -> post-read barrier is
    // redundant (write-after-read hazard is thread-local).
    auto rot = [&](auto from, auto to) {
#pragma unroll
        for (int r = 0; r < 4; ++r) { int s = SW(from(r)); sre[s] = ar[r]; sim_[s] = ai[r]; }
        __syncthreads();
#pragma unroll
        for (int r = 0; r < 4; ++r) { int s = SW(to(r)); ar[r] = sre[s]; ai[r] = sim_[s]; }
    };
    auto Ua = [&](int l, int w) -> const float2* { return &sUa[(l * 11 + w) * 4]; };
    auto Ub = [&](int l, int w) -> const float2* { return &sUb[(l * 11 + w) * 4]; };
    auto czfold = [&](unsigned M, auto gidx) {
#pragma unroll
        for (int r = 0; r < 4; ++r) {
            int i = gidx(r);
            if (__popc(i & (i >> 1) & M) & 1) { ar[r] = -ar[r]; ai[r] = -ai[r]; }
        }
    };
    auto gV1 = [&](int r) { return V1(r) << 7; };
    auto gV2 = [&](int r) { return V2(r) << 7; };
    auto gV3 = [&](int r) { return V3(r) << 7; };
    auto gT1 = [&](int r) { return (gc << 11) | T1(r); };
    auto gT2 = [&](int r) { return (gc << 11) | T2(r); };
    auto gT6 = [&](int r) { return (gc << 11) | T6(r); };

    // ================= PHASE 1 (every block, own circuit) ==================
    // seg1 [V1, reg {w1,w2}]: product init (L0 all), CZ0, L1 w1,w2, L1 lane
    {
        float2 com = make_float2(1.f, 0.f);
        const float2* u0 = Ua(0, 0); com = cmulf(com, wv0 ? u0[2] : u0[0]);
        const float2* u3 = Ua(0, 3); com = cmulf(com, wv1 ? u3[2] : u3[0]);
        const float2* u4 = Ua(0, 4); com = cmulf(com, wv2 ? u4[2] : u4[0]);
#pragma unroll
        for (int j = 0; j < 6; ++j) {
            const float2* u = Ua(0, 5 + j);
            com = cmulf(com, ((lane >> j) & 1) ? u[2] : u[0]);
        }
        const float2* u1 = Ua(0, 1); const float2* u2 = Ua(0, 2);
#pragma unroll
        for (int r = 0; r < 4; ++r) {
            float2 f = cmulf((r & 1) ? u1[2] : u1[0], (r & 2) ? u2[2] : u2[0]);
            f = cmulf(com, f);
            ar[r] = f.x; ai[r] = f.y;
        }
    }
    czfold(0x1FF80u, gV1);                        // CZ0
    reg_gate4<1>(ar, ai, Ua(1, 1));
    reg_gate4<2>(ar, ai, Ua(1, 2));
#pragma unroll
    for (int j = 0; j < 6; ++j) lane_gate4(ar, ai, Ua(1, 5 + j), lane, j);
    rot(V1, V2);
    // seg2 [V2, reg {w3,w4}]
    reg_gate4<1>(ar, ai, Ua(1, 3));
    reg_gate4<2>(ar, ai, Ua(1, 4));
    czfold(0x1FF00u, gV2);                        // CZ1
    reg_gate4<1>(ar, ai, Ua(2, 3));
    reg_gate4<2>(ar, ai, Ua(2, 4));
#pragma unroll
    for (int j = 0; j < 6; ++j) lane_gate4(ar, ai, Ua(2, 5 + j), lane, j);
    rot(V2, V3);
    // seg3 [V3, reg {w2,w3}]
    reg_gate4<1>(ar, ai, Ua(2, 2));               // L2 w2 (after CZ1, before CZ2)
    czfold(0x1FE00u, gV3);                        // CZ2
    reg_gate4<2>(ar, ai, Ua(3, 3));               // L3 w3
#pragma unroll
    for (int j = 0; j < 6; ++j) lane_gate4(ar, ai, Ua(3, 5 + j), lane, j);
    rot(V3, V2);
    // seg4 [V2, reg {w3,w4}]
    reg_gate4<2>(ar, ai, Ua(3, 4));               // L3 w4
    czfold(0x1FC00u, gV2);                        // CZ3
    reg_gate4<2>(ar, ai, Ua(4, 4));               // L4 w4
#pragma unroll
    for (int j = 0; j < 6; ++j) lane_gate4(ar, ai, Ua(4, 5 + j), lane, j);
    rot(V2, V1);
    // seg5 [V1]
    czfold(0x1F800u, gV1);                        // CZ4 phase-1 part
    if (c == 1) {                                 // consumer: RX(-d) on q0..5
#pragma unroll
        for (int j = 0; j < 6; ++j) lane_gate4(ar, ai, &sDa[j * 4], lane, j);
    }
    // transition: publish phase-1 vector (V1), sparse-gather phase-2 init (T1)
#pragma unroll
    for (int r = 0; r < 4; ++r) { int s = SW(V1(r)); sre[s] = ar[r]; sim_[s] = ai[r]; }
    __syncthreads();
#pragma unroll
    for (int r = 0; r < 4; ++r) {
        int x = T1(r);
        if ((x & 127) == 0) {
            int Wv = (gc << 4) | (x >> 7);
            int s = SW(Wv);
            ar[r] = sre[s]; ai[r] = sim_[s];
        } else { ar[r] = 0.f; ai[r] = 0.f; }
    }
    __syncthreads();   // gather reads non-owned slots: barrier before next write

    // ================= PHASE 2 (chunk gc, circuit c) =======================
    // t1 [T1, reg {6,7}]
#pragma unroll
    for (int j = 0; j < 6; ++j) lane_gate4(ar, ai, Ub(0, j), lane, j);
    reg_gate4<1>(ar, ai, Ub(0, 6));
    czfold(0x7Fu, gT1);                           // CZ0
#pragma unroll
    for (int j = 0; j < 6; ++j) lane_gate4(ar, ai, Ub(1, j), lane, j);
    reg_gate4<1>(ar, ai, Ub(1, 6));
    reg_gate4<2>(ar, ai, Ub(1, 7));
    rot(T1, T2);
    // t2 [T2, reg {8,9}]
    czfold(0xFFu, gT2);                           // CZ1
#pragma unroll
    for (int j = 0; j < 6; ++j) lane_gate4(ar, ai, Ub(2, j), lane, j);
    reg_gate4<1>(ar, ai, Ub(2, 8));
    rot(T2, T1);
    // t3 [T1]
    reg_gate4<1>(ar, ai, Ub(2, 6));
    reg_gate4<2>(ar, ai, Ub(2, 7));
    czfold(0x1FFu, gT1);                          // CZ2
#pragma unroll
    for (int j = 0; j < 6; ++j) lane_gate4(ar, ai, Ub(3, j), lane, j);
    reg_gate4<1>(ar, ai, Ub(3, 6));
    reg_gate4<2>(ar, ai, Ub(3, 7));
    rot(T1, T2);
    // t4 [T2]
    reg_gate4<1>(ar, ai, Ub(3, 8));
    reg_gate4<2>(ar, ai, Ub(3, 9));
    czfold(0x3FFu, gT2);                          // CZ3
#pragma unroll
    for (int j = 0; j < 6; ++j) lane_gate4(ar, ai, Ub(4, j), lane, j);
    reg_gate4<1>(ar, ai, Ub(4, 8));
    reg_gate4<2>(ar, ai, Ub(4, 9));
    rot(T2, T1);
    // t5 [T1]
    reg_gate4<1>(ar, ai, Ub(4, 6));
    reg_gate4<2>(ar, ai, Ub(4, 7));
    czfold(0xE0u, gT1);                           // CZ4 part: pairs (5,6)(6,7)(7,8)
    rot(T1, T6);
    // t6 [T6, reg {9,10}]
    reg_gate4<2>(ar, ai, Ub(4, 10));              // L4 w10
    czfold(0x71Fu, gT6);                          // CZ4 part: (0,1)..(4,5),(8,9),(9,10),(10,11)

    if (c == 0) {
        // -------- producer: store chunk (T6 layout), release flag --------
#pragma unroll
        for (int r = 0; r < 4; ++r) {
            int i = (gc << 11) | T6(r);
            states[i] = make_float2(ar[r], ai[r]);
        }
        __syncthreads();            // all waves' stores issued
        if (t == 0) {
            __hip_atomic_store(&flags[gc * 16], MAGIC, __ATOMIC_RELEASE,
                               __HIP_MEMORY_SCOPE_AGENT);
        }
    } else {
        // consumer: finish RX(-d), then poll (producers are ahead)
#pragma unroll
        for (int j = 0; j < 5; ++j) lane_gate4(ar, ai, &sDb[j * 4], lane, j);
        reg_gate4<1>(ar, ai, &sDb[9 * 4]);
        reg_gate4<2>(ar, ai, &sDb[10 * 4]);
        rot(T6, T1);
        // t7 [T1]
        lane_gate4(ar, ai, &sDb[5 * 4], lane, 5);
        reg_gate4<1>(ar, ai, &sDb[6 * 4]);
        reg_gate4<2>(ar, ai, &sDb[7 * 4]);
        rot(T1, T8);
        // t8 [T8, reg {8,10}]
        reg_gate4<1>(ar, ai, &sDb[8 * 4]);

        float d6 = iscale[5 * NQ + 6] * (x1[6] - x2[6]);
        float sn6, cs6;
        sincosf(d6 * 0.5f, &sn6, &cs6);
        float cf = cs6, sf = sn6;

        if (t == 0) {
            // RELAXED agent-scope polls read the LLC directly (no per-poll
            // cache invalidate); one acquire fence after all flags confirm.
            while (__hip_atomic_load(&flags[gc * 16], __ATOMIC_RELAXED,
                                     __HIP_MEMORY_SCOPE_AGENT) != MAGIC)
                __builtin_amdgcn_s_sleep(1);
            while (__hip_atomic_load(&flags[(gc ^ 1) * 16], __ATOMIC_RELAXED,
                                     __HIP_MEMORY_SCOPE_AGENT) != MAGIC)
                __builtin_amdgcn_s_sleep(1);
            while (__hip_atomic_load(&flags[128 * 16], __ATOMIC_RELAXED,
                                     __HIP_MEMORY_SCOPE_AGENT) != MAGIC)
                __builtin_amdgcn_s_sleep(1);
            __builtin_amdgcn_fence(__ATOMIC_ACQUIRE, "agent");
        }
        __syncthreads();            // whole block proceeds after the fence

        double accr = 0.0, acci = 0.0;
#pragma unroll
        for (int r = 0; r < 4; ++r) {
            int i = (gc << 11) | T8(r);
            float2 p1 = states[i];
            float2 pp = states[i ^ 2048];
            // (RX6(+d6) psi1)[i] = cf*psi1[i] - i*sf*psi1[i^b11]
            float gr = cf * p1.x + sf * pp.y;
            float gi = cf * p1.y - sf * pp.x;
            // conj(a2) * psi1'
            accr += (double)ar[r] * gr + (double)ai[r] * gi;
            acci += (double)ar[r] * gi - (double)ai[r] * gr;
        }
        for (int o = 32; o > 0; o >>= 1) {
            accr += __shfl_down(accr, o, 64);
            acci += __shfl_down(acci, o, 64);
        }
        if (lane == 0) { wr[wave] = accr; wi[wave] = acci; }
        __syncthreads();
        if (t == 0) {
            double br = 0.0, bi = 0.0;
#pragma unroll
            for (int w = 0; w < 8; ++w) { br += wr[w]; bi += wi[w]; }
            atomicAdd(&acc[0], br);
            atomicAdd(&acc[1], bi);
            __threadfence();
            unsigned old = atomicAdd(cnt, 1u);
            if (old == 127u) {
                double fr = atomicAdd(&acc[0], 0.0);
                double fi = atomicAdd(&acc[1], 0.0);
                out[0] = (float)(fr * fr + fi * fi);
            }
        }
    }
}

// ---------------- launch ----------------------------------------------------
extern "C" void kernel_launch(void* const* d_in, const int* in_sizes, int n_in,
                              void* d_out, int out_size, void* d_ws, size_t ws_size,
                              hipStream_t stream)
{
    const float* x1 = (const float*)d_in[0];
    const float* x2 = (const float*)d_in[1];
    const float* iscale = (const float*)d_in[2];
    const float* var = (const float*)d_in[3];
    float* out = (float*)d_out;

    // ws layout: [8192] acc (2 doubles); [8320] cnt; [16384] flags (129 x 64B
    // slots, ends 24640); [65536, 65536+2MB) psi1 statevector.
    double*   acc    = (double*)((char*)d_ws + 8192);
    unsigned* cnt    = (unsigned*)((char*)d_ws + 8320);
    unsigned* flags  = (unsigned*)((char*)d_ws + 16384);
    float2*   states = (float2*)((char*)d_ws + 65536);

    sim_kernel<<<256, TPB, 0, stream>>>(states, x1, x2, iscale, var,
                                        acc, cnt, flags, out);
}